// Round 1
// baseline (167.933 us; speedup 1.0000x reference)
//
#include <hip/hip_runtime.h>

#define BATCH 256
#define SLEN  2048
#define DDIM  64
#define MAXK  8

__global__ __launch_bounds__(256) void wave_kernel(
    const int*   __restrict__ seqs,   // [B,S] int32, right-padded with 0
    const float* __restrict__ emb,    // [B,S,D] fp32
    const int*   __restrict__ kptr,   // scalar k
    float*       __restrict__ out)    // [B,D] fp32
{
    __shared__ int   sseq[SLEN];
    __shared__ float avg[SLEN];
    __shared__ int   sL;
    __shared__ int   anchors[MAXK];
    __shared__ int   counts[MAXK];
    __shared__ float winv[MAXK];
    __shared__ float partial[4][DDIM];

    const int b    = blockIdx.x;
    const int tid  = threadIdx.x;
    const int lane = tid & 63;
    const int wave = tid >> 6;
    const int k    = kptr[0];          // == 5 for this problem; handle k<=8

    if (tid == 0) sL = 0;
    if (tid < MAXK) counts[tid] = 0;
    for (int s = tid; s < SLEN; s += 256) avg[s] = 0.0f;
    __syncthreads();

    // ---- Phase 1: stage seqs into LDS, compute L = count(nonzero) ----
    int cnt = 0;
    for (int s = tid; s < SLEN; s += 256) {
        int v = seqs[b * SLEN + s];
        sseq[s] = v;
        cnt += (v != 0);
    }
    #pragma unroll
    for (int off = 32; off; off >>= 1) cnt += __shfl_down(cnt, off, 64);
    if (lane == 0) atomicAdd(&sL, cnt);
    __syncthreads();

    const int L = sL;

    // ---- Phase 2: anchors a_j = sseq[max(L-1-j,0)] ----
    if (tid < k) {
        int a = L - 1 - tid;
        if (a < 0) a = 0;
        anchors[tid] = sseq[a];
    }
    __syncthreads();

    int aj[MAXK];
    #pragma unroll
    for (int j = 0; j < MAXK; ++j)
        aj[j] = (j < k) ? anchors[j] : -1;   // -1 never matches (vals >= 0)

    // ---- Phase 3: counts c_j = |{ s < L : sseq[s] == a_j }| ----
    int lc[MAXK];
    #pragma unroll
    for (int j = 0; j < MAXK; ++j) lc[j] = 0;
    for (int s = tid; s < L; s += 256) {
        int v = sseq[s];
        #pragma unroll
        for (int j = 0; j < MAXK; ++j)
            if (v == aj[j]) lc[j]++;
    }
    #pragma unroll
    for (int j = 0; j < MAXK; ++j)
        if (j < k && lc[j]) atomicAdd(&counts[j], lc[j]);
    __syncthreads();

    if (tid < k) winv[tid] = 1.0f / ((float)k * (float)counts[tid]);
    __syncthreads();

    float wj[MAXK];
    #pragma unroll
    for (int j = 0; j < MAXK; ++j)
        wj[j] = (j < k) ? winv[j] : 0.0f;

    // ---- Phase 4: scatter weights into avg[] (LDS float atomics) ----
    for (int s = tid; s < L; s += 256) {
        int v = sseq[s];
        #pragma unroll
        for (int j = 0; j < MAXK; ++j) {
            if (v == aj[j]) {
                int r = s + j + 1;
                if (r < L) atomicAdd(&avg[r], wj[j]);
            }
        }
    }
    __syncthreads();

    // ---- Phase 5: sparse weighted pooling.
    // Wave w scans s in [w*512,(w+1)*512); 64 entries per ballot step;
    // only nonzero weights trigger a coalesced row gather of emb.
    float acc = 0.0f;
    const float* embb = emb + (size_t)b * SLEN * DDIM;
    for (int sb = wave * 512; sb < (wave + 1) * 512; sb += 64) {
        float wv = avg[sb + lane];
        unsigned long long m = __ballot(wv != 0.0f);
        while (m) {
            int i = __ffsll((long long)m) - 1;
            m &= (m - 1);
            float wgt = avg[sb + i];           // broadcast LDS read
            acc += wgt * embb[(sb + i) * DDIM + lane];
        }
    }
    partial[wave][lane] = acc;
    __syncthreads();

    if (wave == 0) {
        float o = partial[0][lane] + partial[1][lane]
                + partial[2][lane] + partial[3][lane];
        out[b * DDIM + lane] = o;
    }
}

extern "C" void kernel_launch(void* const* d_in, const int* in_sizes, int n_in,
                              void* d_out, int out_size, void* d_ws, size_t ws_size,
                              hipStream_t stream) {
    const int*   seqs = (const int*)d_in[0];
    const float* emb  = (const float*)d_in[1];
    const int*   kptr = (const int*)d_in[2];
    float*       out  = (float*)d_out;

    wave_kernel<<<BATCH, 256, 0, stream>>>(seqs, emb, kptr, out);
}

// Round 2
// 164.075 us; speedup vs baseline: 1.0235x; 1.0235x over previous
//
#include <hip/hip_runtime.h>

#define BATCH 256
#define SLEN  2048
#define DDIM  64
#define MAXK  8
#define EVCAP 2048   // sparse event capacity; expected ~1-2 events/block

__global__ __launch_bounds__(256) void wave_kernel(
    const int*   __restrict__ seqs,   // [B,S] int32, right-padded with 0
    const float* __restrict__ emb,    // [B,S,D] fp32
    const int*   __restrict__ kptr,   // scalar k
    float*       __restrict__ out)    // [B,D] fp32
{
    __shared__ int sseq[SLEN];
    __shared__ int wcnt[4];           // per-wave nonzero counts
    __shared__ int counts[MAXK];      // c_j match counts
    __shared__ int nev;               // event list size
    __shared__ int ev[EVCAP];         // packed events: r | (j<<16)

    const int b    = blockIdx.x;
    const int tid  = threadIdx.x;
    const int lane = tid & 63;
    const int wave = tid >> 6;
    const int k    = kptr[0];         // == 5 here; supports k<=8

    if (tid == 0) nev = 0;
    if (tid < MAXK) counts[tid] = 0;

    // ---- Stage seqs into LDS via int4; keep own 8 values in registers ----
    const int4* sp = (const int4*)(seqs + (size_t)b * SLEN);
    int4 a0 = sp[2 * tid];
    int4 a1 = sp[2 * tid + 1];
    ((int4*)sseq)[2 * tid]     = a0;
    ((int4*)sseq)[2 * tid + 1] = a1;

    int vr[8] = {a0.x, a0.y, a0.z, a0.w, a1.x, a1.y, a1.z, a1.w};
    int cnt = 0;
    #pragma unroll
    for (int i = 0; i < 8; ++i) cnt += (vr[i] != 0);
    #pragma unroll
    for (int off = 32; off; off >>= 1) cnt += __shfl_down(cnt, off, 64);
    if (lane == 0) wcnt[wave] = cnt;

    __syncthreads();   // barrier 1: sseq, wcnt, counts/nev init all visible

    const int L = wcnt[0] + wcnt[1] + wcnt[2] + wcnt[3];

    // ---- Anchors (LDS broadcast reads; no extra barrier needed) ----
    int aj[MAXK];
    #pragma unroll
    for (int j = 0; j < MAXK; ++j) {
        int a = L - 1 - j;
        if (a < 0) a = 0;
        aj[j] = (j < k) ? sseq[a] : 0;   // 0 sentinel never matches v!=0
    }

    // ---- Scan own registers: counts + sparse events (rare) ----
    const int sbase = tid * 8;
    #pragma unroll
    for (int i = 0; i < 8; ++i) {
        int v = vr[i];
        if (v != 0) {
            #pragma unroll
            for (int j = 0; j < MAXK; ++j) {
                if (v == aj[j]) {
                    atomicAdd(&counts[j], 1);
                    int r = sbase + i + j + 1;
                    if (r < L) {
                        int e = atomicAdd(&nev, 1);
                        if (e < EVCAP) ev[e] = r | (j << 16);
                    }
                }
            }
        }
    }

    __syncthreads();   // barrier 2: counts + events final

    // ---- Sparse pooling: wave 0 processes the (few) events ----
    if (wave == 0) {
        int n = nev;
        if (n > EVCAP) n = EVCAP;
        float acc = 0.0f;
        const float* embb = emb + (size_t)b * SLEN * DDIM;
        for (int e = 0; e < n; ++e) {
            int p = ev[e];
            int r = p & 0xFFFF;
            int j = p >> 16;
            float w = 1.0f / ((float)k * (float)counts[j]);
            acc += w * embb[r * DDIM + lane];
        }
        out[b * DDIM + lane] = acc;
    }
}

extern "C" void kernel_launch(void* const* d_in, const int* in_sizes, int n_in,
                              void* d_out, int out_size, void* d_ws, size_t ws_size,
                              hipStream_t stream) {
    const int*   seqs = (const int*)d_in[0];
    const float* emb  = (const float*)d_in[1];
    const int*   kptr = (const int*)d_in[2];
    float*       out  = (float*)d_out;

    wave_kernel<<<BATCH, 256, 0, stream>>>(seqs, emb, kptr, out);
}